// Round 1
// baseline (2181.470 us; speedup 1.0000x reference)
//
#include <hip/hip_runtime.h>
#include <math.h>

// ---------------------------------------------------------------------------
// AGNN stack: h=relu(x@W1+b1); 32x AGNNConv(beta=1); log_softmax(h@W2+b2)
// N=100000, F=512, H=32, C=40, E=3200000 (+N self loops)
// R6: cosine attention is bounded (|alpha| <= 1), so softmax uses a FIXED
//     shift exp(alpha-1) -> the entire per-chunk online-max/sum cross-lane
//     machinery (8 ds_swizzle + 2 exp + rescale per chunk) is deleted.
//     s becomes per-slot state merged once at wave end. Dot reduce moved
//     from ds_swizzle to DPP quad_perm (VALU). Gather prefetch depth 2.
// ---------------------------------------------------------------------------

#define HDIM 32
#define NBMAX 1024   // bucket table size (needs N <= 128*1024)
#define BSH 7        // 128 dsts per bucket
#define CHUNK 32768  // edges per partition block
#define TP 68        // padded gemm1 tile stride (floats)

typedef _Float16 f16;
typedef _Float16 v2h __attribute__((ext_vector_type(2)));

struct __attribute__((aligned(16))) H8 { v2h p[4]; };  // one fp16 half-row (8 elems)
struct __attribute__((aligned(8)))  H4 { v2h p[2]; };  // 4 fp16 elems

#if defined(__has_builtin)
#if __has_builtin(__builtin_amdgcn_fdot2)
#define FDOT2(a, b, c) __builtin_amdgcn_fdot2((a), (b), (c), false)
#endif
#if __has_builtin(__builtin_amdgcn_update_dpp)
#define HAS_DPP 1
#endif
#endif
#ifndef FDOT2
#define FDOT2(a, b, c) fmaf((float)(a)[1], (float)(b)[1], fmaf((float)(a)[0], (float)(b)[0], (c)))
#endif

// sum over each aligned 4-lane quad (lanes l^1, l^2) — DPP, no LDS pipe
static __device__ __forceinline__ float quad_sum(float x) {
#ifdef HAS_DPP
    x += __int_as_float(__builtin_amdgcn_update_dpp(
        0, __float_as_int(x), 0xB1 /*quad_perm [1,0,3,2]*/, 0xF, 0xF, true));
    x += __int_as_float(__builtin_amdgcn_update_dpp(
        0, __float_as_int(x), 0x4E /*quad_perm [2,3,0,1]*/, 0xF, 0xF, true));
#else
    x += __shfl_xor(x, 1);
    x += __shfl_xor(x, 2);
#endif
    return x;
}

static __device__ __forceinline__ int eread(const int* __restrict__ e, int i64, long long idx) {
    return i64 ? e[2 * idx] : e[idx];
}

__global__ void k_flag(const int* __restrict__ e, int* __restrict__ flag) {
    if (blockIdx.x == 0 && threadIdx.x == 0) {
        int z = 0;
        for (int k = 0; k < 64; ++k) z |= e[2 * k + 1];
        *flag = (z == 0) ? 1 : 0;
    }
}

__global__ void k_zero(int* __restrict__ p, int n) {
    int i = blockIdx.x * blockDim.x + threadIdx.x;
    if (i < n) p[i] = 0;
}

// Pass 1: per-block LDS histogram over dst buckets + global reserve.
__launch_bounds__(256) __global__
void k_hist(const int* __restrict__ e, const int* __restrict__ flag,
            int* __restrict__ gc, int* __restrict__ blockOffs,
            long long E, long long M) {
    __shared__ int bh[NBMAX];
    for (int t = threadIdx.x; t < NBMAX; t += 256) bh[t] = 0;
    __syncthreads();
    int i64 = *flag;
    long long base = (long long)blockIdx.x * CHUNK;
    long long end = base + CHUNK < M ? base + CHUNK : M;
    for (long long m = base + threadIdx.x; m < end; m += 256) {
        int d = (m < E) ? eread(e, i64, E + m) : (int)(m - E);
        atomicAdd(&bh[d >> BSH], 1);
    }
    __syncthreads();
    for (int t = threadIdx.x; t < NBMAX; t += 256) {
        int c = bh[t];
        int off = 0;
        if (c) off = atomicAdd(&gc[t], c);
        blockOffs[(size_t)blockIdx.x * NBMAX + t] = off;
    }
}

__launch_bounds__(256) __global__
void k_bscan(const int* __restrict__ gc, int* __restrict__ bbase,
             int* __restrict__ rp, int N) {
    __shared__ int lds[256];
    int t = threadIdx.x;
    int v[4];
#pragma unroll
    for (int d = 0; d < 4; ++d) v[d] = gc[t * 4 + d];
    int tsum = v[0] + v[1] + v[2] + v[3];
    lds[t] = tsum;
    __syncthreads();
    int acc = tsum;
    for (int sh = 1; sh < 256; sh <<= 1) {
        int x = (t >= sh) ? lds[t - sh] : 0;
        __syncthreads();
        acc += x;
        lds[t] = acc;
        __syncthreads();
    }
    if (t == 255) { rp[N] = acc; bbase[NBMAX] = acc; }
    int run = acc - tsum;
#pragma unroll
    for (int d = 0; d < 4; ++d) { bbase[t * 4 + d] = run; run += v[d]; }
}

// Pass 2: partition edges into bucket regions.
__launch_bounds__(256) __global__
void k_part(const int* __restrict__ e, const int* __restrict__ flag,
            const int* __restrict__ bbase, const int* __restrict__ blockOffs,
            int2* __restrict__ pair, long long E, long long M) {
    __shared__ int cur[NBMAX];
    for (int t = threadIdx.x; t < NBMAX; t += 256)
        cur[t] = bbase[t] + blockOffs[(size_t)blockIdx.x * NBMAX + t];
    __syncthreads();
    int i64 = *flag;
    long long base = (long long)blockIdx.x * CHUNK;
    long long end = base + CHUNK < M ? base + CHUNK : M;
    for (long long m = base + threadIdx.x; m < end; m += 256) {
        int s, d;
        if (m < E) { s = eread(e, i64, m); d = eread(e, i64, E + m); }
        else { s = d = (int)(m - E); }
        int pos = atomicAdd(&cur[d >> BSH], 1);
        pair[pos] = make_int2(s, d);
    }
}

// Pass 3: one block per bucket -> fine CSR (rp + col), all LDS atomics.
__launch_bounds__(256) __global__
void k_fine(const int2* __restrict__ pair, const int* __restrict__ bbase,
            int* __restrict__ rp, int* __restrict__ col, int N) {
    __shared__ int cnt[128];
    __shared__ int sc[128];
    int b = blockIdx.x;
    int beg = bbase[b];
    int end = bbase[b + 1];
    int t = threadIdx.x;
    if (t < 128) cnt[t] = 0;
    __syncthreads();
    for (int k = beg + t; k < end; k += 256)
        atomicAdd(&cnt[pair[k].y & 127], 1);
    __syncthreads();
    if (t < 128) sc[t] = cnt[t];
    __syncthreads();
    for (int sh = 1; sh < 128; sh <<= 1) {
        int x = 0;
        if (t < 128 && t >= sh) x = sc[t - sh];
        __syncthreads();
        if (t < 128) sc[t] += x;
        __syncthreads();
    }
    if (t < 128) {
        int basepos = beg + sc[t] - cnt[t];
        int d = (b << BSH) + t;
        if (d < N) rp[d] = basepos;
        cnt[t] = basepos;
    }
    __syncthreads();
    for (int k = beg + t; k < end; k += 256) {
        int2 p = pair[k];
        int pos = atomicAdd(&cnt[p.y & 127], 1);
        col[pos] = p.x;
    }
}

// h = relu(x @ W1 + b1) + fused inv_norm, fp16 h output.
// Thread (cg=tid&7, ty=tid>>3) computes rows {ty, ty+32} x cols {4cg..4cg+3}.
// LDS amplification 8x; tile stride 68 -> conflict-free reads.
__launch_bounds__(256) __global__
void k_gemm1(const float* __restrict__ x, const float* __restrict__ W1,
             const float* __restrict__ b1, f16* __restrict__ h,
             float* __restrict__ invn, int N) {
    __shared__ float tile[64 * TP];  // 17408 B
    int tid = threadIdx.x;
    int cg = tid & 7;   // c = 4*cg .. 4*cg+3
    int ty = tid >> 3;  // 0..31
    int rbase = blockIdx.x * 64;
    float4 bias = *(const float4*)(b1 + 4 * cg);
    float acc[2][4];
#pragma unroll
    for (int m = 0; m < 2; ++m) {
        acc[m][0] = bias.x; acc[m][1] = bias.y;
        acc[m][2] = bias.z; acc[m][3] = bias.w;
    }
    for (int kc = 0; kc < 8; ++kc) {
        if (kc) __syncthreads();
#pragma unroll
        for (int j = 0; j < 4; ++j) {
            int f = tid + j * 256;  // float4 slot 0..1023 = 64 rows x 16
            int row = f >> 4, kin = f & 15;
            int r = rbase + row;
            float4 v = make_float4(0.f, 0.f, 0.f, 0.f);
            if (r < N) v = *(const float4*)(x + (size_t)r * 512 + kc * 64 + kin * 4);
            *(float4*)(tile + row * TP + kin * 4) = v;
        }
        __syncthreads();
#pragma unroll
        for (int k4 = 0; k4 < 16; ++k4) {
            int kk = kc * 64 + k4 * 4;
            float4 w0 = *(const float4*)(W1 + (size_t)(kk + 0) * 32 + 4 * cg);
            float4 w1 = *(const float4*)(W1 + (size_t)(kk + 1) * 32 + 4 * cg);
            float4 w2 = *(const float4*)(W1 + (size_t)(kk + 2) * 32 + 4 * cg);
            float4 w3 = *(const float4*)(W1 + (size_t)(kk + 3) * 32 + 4 * cg);
#pragma unroll
            for (int m = 0; m < 2; ++m) {
                float4 xv = *(const float4*)(tile + (ty + 32 * m) * TP + k4 * 4);
                acc[m][0] = fmaf(xv.x, w0.x, acc[m][0]);
                acc[m][1] = fmaf(xv.x, w0.y, acc[m][1]);
                acc[m][2] = fmaf(xv.x, w0.z, acc[m][2]);
                acc[m][3] = fmaf(xv.x, w0.w, acc[m][3]);
                acc[m][0] = fmaf(xv.y, w1.x, acc[m][0]);
                acc[m][1] = fmaf(xv.y, w1.y, acc[m][1]);
                acc[m][2] = fmaf(xv.y, w1.z, acc[m][2]);
                acc[m][3] = fmaf(xv.y, w1.w, acc[m][3]);
                acc[m][0] = fmaf(xv.z, w2.x, acc[m][0]);
                acc[m][1] = fmaf(xv.z, w2.y, acc[m][1]);
                acc[m][2] = fmaf(xv.z, w2.z, acc[m][2]);
                acc[m][3] = fmaf(xv.z, w2.w, acc[m][3]);
                acc[m][0] = fmaf(xv.w, w3.x, acc[m][0]);
                acc[m][1] = fmaf(xv.w, w3.y, acc[m][1]);
                acc[m][2] = fmaf(xv.w, w3.z, acc[m][2]);
                acc[m][3] = fmaf(xv.w, w3.w, acc[m][3]);
            }
        }
    }
#pragma unroll
    for (int m = 0; m < 2; ++m) {
        int r = rbase + ty + 32 * m;
        float hv[4];
        float ss = 0.0f;
#pragma unroll
        for (int j = 0; j < 4; ++j) {
            hv[j] = fmaxf(acc[m][j], 0.0f);
            ss = fmaf(hv[j], hv[j], ss);
        }
        ss += __shfl_xor(ss, 1);
        ss += __shfl_xor(ss, 2);
        ss += __shfl_xor(ss, 4);  // sum over cg
        if (r < N) {
            H4 o;
            o.p[0][0] = (f16)hv[0]; o.p[0][1] = (f16)hv[1];
            o.p[1][0] = (f16)hv[2]; o.p[1][1] = (f16)hv[3];
            *(H4*)(h + (size_t)r * HDIM + 4 * cg) = o;
            if (cg == 0) invn[r] = 1.0f / fmaxf(sqrtf(ss), 1e-12f);
        }
    }
}

// One wave per node; 4 lanes per edge, 16 edges per chunk (fp16 rows = 64B).
// eloc = lane>>2 (edge slot), c8 = lane&3 (8 h-elements each).
// Cosine attention is bounded: |alpha| <= 1 (+fp16 eps), so softmax uses the
// FIXED shift e = exp(alpha - 1) — exact by shift invariance, numerically
// safe (e in [0.135, 1.001]). No online max, no per-chunk cross-slot
// reductions: s is per-slot state merged once at wave end (like acc).
// Dot reduce via DPP quad_perm. Gather pipeline depth 2.
__launch_bounds__(256) __global__
void k_agnn(const f16* __restrict__ h_in, const float* __restrict__ inv_in,
            f16* __restrict__ h_out, float* __restrict__ inv_out,
            const int* __restrict__ rp, const int* __restrict__ col, int N) {
    int wave = threadIdx.x >> 6;
    int lane = threadIdx.x & 63;
    int i = blockIdx.x * 4 + wave;
    if (i >= N) return;
    int beg = rp[i];
    int deg = rp[i + 1] - beg;
    int eloc = lane >> 2;  // 0..15 edge slot
    int c8 = lane & 3;     // element group (8 halfs)
    float inv_i = inv_in[i];
    H8 hi = *(const H8*)(h_in + (size_t)i * HDIM + 8 * c8);
    float s_run = 0.0f;  // per-slot softmax denominator partial
    float acc[8] = {0.f, 0.f, 0.f, 0.f, 0.f, 0.f, 0.f, 0.f};
    int nchunk = (deg + 15) >> 4;
    // col batch covers chunks 0..3
    int cv = (lane < deg) ? col[beg + lane] : 0;
    // depth-2 software pipeline: A = chunk ck, B = chunk ck+1
    H8 rA, rB;
    float iA, iB = 0.0f;
    bool vA, vB = false;
    {
        vA = eloc < deg;  // deg >= 1 always (self loop)
        int s = __shfl(cv, eloc);
        s = vA ? s : 0;
        rA = *(const H8*)(h_in + (size_t)s * HDIM + 8 * c8);
        iA = inv_in[s];
    }
    if (nchunk > 1) {
        int idx = 16 + eloc;
        vB = idx < deg;
        int s = __shfl(cv, 16 | eloc);
        s = vB ? s : 0;
        rB = *(const H8*)(h_in + (size_t)s * HDIM + 8 * c8);
        iB = inv_in[s];
    } else {
        rB = hi;  // keep registers initialized; never consumed
    }
    for (int ck = 0; ck < nchunk; ++ck) {
        H8 rc = rA;
        float ic = iA;
        bool vc = vA;
        rA = rB; iA = iB; vA = vB;
        int nc = ck + 2;
        if (nc < nchunk) {  // wave-uniform branch: issue chunk ck+2
            if ((nc & 3) == 0) {
                int idx64 = nc * 16 + lane;
                cv = (idx64 < deg) ? col[beg + idx64] : 0;
            }
            int idx = nc * 16 + eloc;
            vB = idx < deg;
            int s = __shfl(cv, ((nc & 3) << 4) | eloc);
            s = vB ? s : 0;
            rB = *(const H8*)(h_in + (size_t)s * HDIM + 8 * c8);
            iB = inv_in[s];
        }
        // 32-elem dot within the 4-lane quad (fp32 accum, DPP reduce)
        float dot = 0.0f;
#pragma unroll
        for (int j = 0; j < 4; ++j) dot = FDOT2(rc.p[j], hi.p[j], dot);
        dot = quad_sum(dot);
        // alpha = cos in [-1,1]; fixed-shift softmax term
        float e = vc ? __expf(fmaf(dot, inv_i * ic, -1.0f)) : 0.0f;
        s_run += e;
#pragma unroll
        for (int j = 0; j < 4; ++j) {
            acc[2 * j + 0] = fmaf(e, (float)rc.p[j][0], acc[2 * j + 0]);
            acc[2 * j + 1] = fmaf(e, (float)rc.p[j][1], acc[2 * j + 1]);
        }
    }
    // merge partials across the 16 edge slots (fixed c8)
    float s_tot = s_run;
#pragma unroll
    for (int mask = 4; mask <= 32; mask <<= 1) s_tot += __shfl_xor(s_tot, mask);
#pragma unroll
    for (int mask = 4; mask <= 32; mask <<= 1) {
#pragma unroll
        for (int j = 0; j < 8; ++j) acc[j] += __shfl_xor(acc[j], mask);
    }
    float invs = 1.0f / s_tot;  // s_tot >= exp(-2) > 0 (self loop)
    float ss = 0.0f;
#pragma unroll
    for (int j = 0; j < 8; ++j) {
        acc[j] *= invs;
        ss = fmaf(acc[j], acc[j], ss);
    }
    ss = quad_sum(ss);  // sum over the 4 c8 groups
    if (lane < 4) {  // eloc==0: c8 = lane
        H8 o;
#pragma unroll
        for (int j = 0; j < 4; ++j) {
            o.p[j][0] = (f16)acc[2 * j + 0];
            o.p[j][1] = (f16)acc[2 * j + 1];
        }
        *(H8*)(h_out + (size_t)i * HDIM + 8 * lane) = o;
        if (lane == 0) inv_out[i] = 1.0f / fmaxf(sqrtf(ss), 1e-12f);
    }
}

__launch_bounds__(256) __global__
void k_gemm2(const f16* __restrict__ h, const float* __restrict__ W2,
             const float* __restrict__ b2, float* __restrict__ out, int N) {
    int wave = threadIdx.x >> 6;
    int lane = threadIdx.x & 63;
    int i = blockIdx.x * 4 + wave;
    if (i >= N) return;
    bool act = lane < 40;
    float acc = act ? b2[lane] : 0.0f;
    const f16* hr = h + (size_t)i * HDIM;
#pragma unroll
    for (int k = 0; k < HDIM; ++k) {
        float hk = (float)hr[k];
        float w = act ? W2[k * 40 + lane] : 0.0f;
        acc = fmaf(hk, w, acc);
    }
    float logit = act ? acc : -INFINITY;
    float m = logit;
#pragma unroll
    for (int mask = 32; mask >= 1; mask >>= 1) m = fmaxf(m, __shfl_xor(m, mask));
    float e = act ? __expf(logit - m) : 0.0f;
    float s = e;
#pragma unroll
    for (int mask = 32; mask >= 1; mask >>= 1) s += __shfl_xor(s, mask);
    float res = logit - m - __logf(s);
    if (act) out[(size_t)i * 40 + lane] = res;
}

extern "C" void kernel_launch(void* const* d_in, const int* in_sizes, int n_in,
                              void* d_out, int out_size, void* d_ws, size_t ws_size,
                              hipStream_t stream) {
    const float* x  = (const float*)d_in[0];
    const int*   e  = (const int*)d_in[1];
    const float* W1 = (const float*)d_in[2];
    const float* b1 = (const float*)d_in[3];
    const float* W2 = (const float*)d_in[4];
    const float* b2 = (const float*)d_in[5];
    float* out = (float*)d_out;

    const long long E = (long long)in_sizes[1] / 2;
    const int N = in_sizes[0] / 512;  // F_in = 512
    const long long M = E + N;
    const int nblk = (int)((M + CHUNK - 1) / CHUNK);

    char* w = (char*)d_ws;
    auto alloc = [&](size_t bytes) -> void* {
        void* p = (void*)w;
        w += (bytes + 255) & ~(size_t)255;
        return p;
    };
    int*  flag      = (int*)alloc(4);
    int*  gc        = (int*)alloc(NBMAX * 4);
    int*  bbase     = (int*)alloc((NBMAX + 1) * 4);
    int*  blockOffs = (int*)alloc((size_t)nblk * NBMAX * 4);
    int2* pair      = (int2*)alloc((size_t)M * 8);
    int*  rp        = (int*)alloc(((size_t)N + 1) * 4);
    int*  col       = (int*)alloc((size_t)M * 4);
    f16*  hA   = (f16*)alloc((size_t)N * HDIM * 2);
    f16*  hB   = (f16*)alloc((size_t)N * HDIM * 2);
    float* invA = (float*)alloc((size_t)N * 4);
    float* invB = (float*)alloc((size_t)N * 4);
    if ((size_t)(w - (char*)d_ws) > ws_size) return;

    k_flag<<<1, 64, 0, stream>>>(e, flag);
    k_zero<<<(NBMAX + 255) / 256, 256, 0, stream>>>(gc, NBMAX);
    k_hist<<<nblk, 256, 0, stream>>>(e, flag, gc, blockOffs, E, M);
    k_bscan<<<1, 256, 0, stream>>>(gc, bbase, rp, N);
    k_part<<<nblk, 256, 0, stream>>>(e, flag, bbase, blockOffs, pair, E, M);
    k_fine<<<NBMAX, 256, 0, stream>>>(pair, bbase, rp, col, N);

    k_gemm1<<<(N + 63) / 64, 256, 0, stream>>>(x, W1, b1, hA, invA, N);

    f16 *hin = hA, *hout = hB;
    float *iin = invA, *iout = invB;
    for (int l = 0; l < 32; ++l) {
        k_agnn<<<(N + 3) / 4, 256, 0, stream>>>(hin, iin, hout, iout, rp, col, N);
        f16* t = hin; hin = hout; hout = t;
        float* ti = iin; iin = iout; iout = ti;
    }
    k_gemm2<<<(N + 3) / 4, 256, 0, stream>>>(hin, W2, b2, out, N);
}